// Round 12
// baseline (174.176 us; speedup 1.0000x reference)
//
#include <hip/hip_runtime.h>
#include <math.h>

// Gaussians covariance, MI355X. cov = s^2 * I exactly (isotropic scales,
// R orthogonal) -> problem is the exact 3-NN search over N^2 pairs.
//
// R12 (vs R11: 71.6us; kernels model at ~8-10us, fill ~42, so ~15-20us is
// inter-dispatch overhead -> remove a dispatch):
//  - FUSED: finalize now runs inside cellmin via last-block-does-reduction.
//    After the ws4 store: device release fence + atomicAdd on a per-i-block
//    counter; the 24th arrival (old==23) acquire-fences and finalizes its
//    256 i's inline (thread t owns i = iblk+t: 24 coalesced float4 loads,
//    top-4 cells, exact diff-form rescan of 4x16 consecutive j's, s^2*I).
//    Counter init is poison-proof: every block CASes 0xAAAAAAAA->0 first
//    (succeeds exactly once; no-op once value < 24), so old==23 is unique.
//  - pass A core unchanged from R11: mfma_f32_32x32x16_f16 tiles of
//    qj - xi.xj via compensated fp16 (products exact in fp32), 1 v_min per
//    pair, 768 blocked cells of 16 consecutive j's, 10-bit id in mantissa.
// NOTE: ~42us of the timed window is the harness's 256MiB ws poison fill.

#define N_PTS 12288
#define CHUNK 512               // j's per chunk
#define NCH   (N_PTS / CHUNK)   // 24 chunks
#define CELLJ 16                // consecutive j's per cell; 32 cells/chunk
#define IBLK  256               // i's per pass-A block
#define NIB   (N_PTS / IBLK)    // 48
#define TSTR  257               // LDS transpose stride (dwords)
#define CMASK 1023u             // 10-bit cell id

typedef _Float16 half8  __attribute__((ext_vector_type(8)));
typedef float    f32x16 __attribute__((ext_vector_type(16)));

__device__ __forceinline__ void ins4(float d, float& a0, float& a1,
                                     float& a2, float& a3) {
    // insert d into sorted a0<=a1<=a2<=a3, keep 4 smallest (4 VALU)
    const float n0 = fminf(a0, d);
    const float n1 = __builtin_amdgcn_fmed3f(a0, a1, d);
    const float n2 = __builtin_amdgcn_fmed3f(a1, a2, d);
    const float n3 = __builtin_amdgcn_fmed3f(a2, a3, d);
    a0 = n0; a1 = n1; a2 = n2; a3 = n3;
}

__global__ __launch_bounds__(256, 4) void cellmin_fused(
    const float* __restrict__ pts, float4* __restrict__ ws4,
    unsigned* __restrict__ cnt, float* __restrict__ out)
{
    // union: sB (16 b-iters x 64 lane-slots x 8 halves = 16KB) during MFMA,
    // then sT (32 cells x 256 i, stride TSTR = 32.9KB) for the transpose
    __shared__ __align__(16) unsigned char shmem[32 * TSTR * 4];
    _Float16* sB = (_Float16*)shmem;
    float*    sT = (float*)shmem;
    __shared__ unsigned s_old;

    const int t    = threadIdx.x;
    const int iblk = blockIdx.x * IBLK;
    const int g    = blockIdx.y;           // chunk 0..23

    // ---- stage B fragments: col c holds j = g*512 + c*16 + b (blocked) ----
    // K slots (h=0): k0-2 = -bh(xyz) (vs ah), k3-5 = -bh(xyz) (vs al),
    //                k6-7 = -bl(x,y) (vs ah)
    //        (h=1): k8 = -bl_z (vs ah_z), k9 = qh, k10 = ql (vs 1), rest 0
    for (int idx = t; idx < CHUNK; idx += 256) {
        const int col = idx & 31, b = idx >> 5;
        const int j = g * CHUNK + col * CELLJ + b;
        const float x = pts[3 * j + 0], y = pts[3 * j + 1], z = pts[3 * j + 2];
        const _Float16 bhx = (_Float16)x, bhy = (_Float16)y, bhz = (_Float16)z;
        const _Float16 blx = (_Float16)(x - (float)bhx);
        const _Float16 bly = (_Float16)(y - (float)bhy);
        const _Float16 blz = (_Float16)(z - (float)bhz);
        const float q = 0.5f * fmaf(z, z, fmaf(y, y, x * x));
        const _Float16 qh = (_Float16)q;
        const _Float16 ql = (_Float16)(q - (float)qh);
        half8 s0;
        s0[0] = -bhx; s0[1] = -bhy; s0[2] = -bhz;
        s0[3] = -bhx; s0[4] = -bhy; s0[5] = -bhz;
        s0[6] = -blx; s0[7] = -bly;
        half8 s1 = (_Float16)0;
        s1[0] = -blz; s1[1] = qh; s1[2] = ql;
        *(half8*)&sB[(b * 64 + col) * 8]      = s0;   // h=0 lanes
        *(half8*)&sB[(b * 64 + 32 + col) * 8] = s1;   // h=1 lanes
    }

    // own-i q (thread t owns i = iblk + t for the reduce/store phase)
    float qi_t;
    {
        const float x = pts[3 * (iblk + t) + 0];
        const float y = pts[3 * (iblk + t) + 1];
        const float z = pts[3 * (iblk + t) + 2];
        qi_t = 0.5f * fmaf(z, z, fmaf(y, y, x * x));
    }

    // ---- A fragments: wave w owns i-tiles 2w, 2w+1 (32 i's each) ----
    const int lane = t & 63;
    const int w    = t >> 6;
    const int m    = lane & 31;    // A row / D col == cell lane
    const int h    = lane >> 5;    // k-half

    half8  afr[2];
    f32x16 mn[2];
    #pragma unroll
    for (int tau = 0; tau < 2; ++tau) {
        const int i = iblk + (2 * w + tau) * 32 + m;
        const float x = pts[3 * i + 0], y = pts[3 * i + 1], z = pts[3 * i + 2];
        const _Float16 ahx = (_Float16)x, ahy = (_Float16)y, ahz = (_Float16)z;
        const _Float16 alx = (_Float16)(x - (float)ahx);
        const _Float16 aly = (_Float16)(y - (float)ahy);
        const _Float16 alz = (_Float16)(z - (float)ahz);
        half8 a = (_Float16)0;
        if (h == 0) {        // k0-7: ah(xyz), al(xyz), ah(x,y)
            a[0] = ahx; a[1] = ahy; a[2] = ahz;
            a[3] = alx; a[4] = aly; a[5] = alz;
            a[6] = ahx; a[7] = ahy;
        } else {             // k8-15: ah_z, 1, 1, zeros
            a[0] = ahz; a[1] = (_Float16)1.0f; a[2] = (_Float16)1.0f;
        }
        afr[tau] = a;
        mn[tau] = INFINITY;
    }
    __syncthreads();

    const f32x16 zero16 = 0.0f;
    #pragma unroll 4
    for (int b = 0; b < 16; ++b) {
        const half8 bf = *(const half8*)&sB[(b * 64 + lane) * 8];
        #pragma unroll
        for (int tau = 0; tau < 2; ++tau) {
            const f32x16 d = __builtin_amdgcn_mfma_f32_32x32x16_f16(
                afr[tau], bf, zero16, 0, 0, 0);
            #pragma unroll
            for (int r = 0; r < 16; ++r)
                mn[tau][r] = fminf(mn[tau][r], d[r]);
        }
    }
    __syncthreads();   // done with sB; reuse as transpose buffer

    // ---- transpose through LDS: sT[cell][i_loc], stride TSTR ----
    #pragma unroll
    for (int tau = 0; tau < 2; ++tau) {
        #pragma unroll
        for (int r = 0; r < 16; ++r) {
            const int row = (r & 3) + 8 * (r >> 2) + 4 * h;
            sT[m * TSTR + (2 * w + tau) * 32 + row] = mn[tau][r];
        }
    }
    __syncthreads();

    // ---- per-i reduce: 32 cells -> top-4 packed, ONE float4 store ----
    float t0 = INFINITY, t1 = INFINITY, t2 = INFINITY, t3 = INFINITY;
    #pragma unroll 8
    for (int c = 0; c < 32; ++c) {
        const float v = sT[c * TSTR + t] + qi_t;
        const unsigned cid = (unsigned)(g * 32 + c);
        const float pv = __uint_as_float((__float_as_uint(v) & ~CMASK) | cid);
        ins4(pv, t0, t1, t2, t3);
    }
    ws4[(size_t)g * N_PTS + (iblk + t)] = make_float4(t0, t1, t2, t3);

    // ---- completion protocol: last chunk-block of this i-block finalizes ----
    __threadfence();                       // release our ws4 row (device scope)
    if (t == 0) {
        unsigned* c = cnt + blockIdx.x;
        atomicCAS(c, 0xAAAAAAAAu, 0u);     // poison-proof init; succeeds once
        s_old = atomicAdd(c, 1u);
    }
    __syncthreads();
    if (s_old != NCH - 1) return;          // not last -> done
    __threadfence();                       // acquire all other blocks' rows

    // ==== inline finalize for i = iblk + t ====
    const int i = iblk + t;

    // top-4 cells over all 24 chunk rows (coalesced float4 loads)
    float c0 = INFINITY, c1 = INFINITY, c2 = INFINITY, c3 = INFINITY;
    #pragma unroll 4
    for (int g2 = 0; g2 < NCH; ++g2) {
        const float4 v = ws4[(size_t)g2 * N_PTS + i];
        ins4(v.x, c0, c1, c2, c3);
        ins4(v.y, c0, c1, c2, c3);
        ins4(v.z, c0, c1, c2, c3);
        ins4(v.w, c0, c1, c2, c3);
    }

    const float px = pts[3 * i + 0];
    const float py = pts[3 * i + 1];
    const float pz = pts[3 * i + 2];

    // exact diff-form rescan of the 4 candidate cells (16 consecutive j each)
    float b0 = INFINITY, b1 = INFINITY, b2 = INFINITY, b3 = INFINITY;
    const unsigned cells[4] = {
        __float_as_uint(c0) & CMASK, __float_as_uint(c1) & CMASK,
        __float_as_uint(c2) & CMASK, __float_as_uint(c3) & CMASK };
    #pragma unroll
    for (int q = 0; q < 4; ++q) {
        const int cid = (int)cells[q];
        const int jb  = (cid >> 5) * CHUNK + (cid & 31) * CELLJ;
        #pragma unroll 4
        for (int n = 0; n < CELLJ; ++n) {
            const int j = jb + n;
            const float dx = px - pts[3 * j + 0];
            const float dy = py - pts[3 * j + 1];
            const float dz = pz - pts[3 * j + 2];
            const float d2 = fmaf(dz, dz, fmaf(dy, dy, dx * dx));
            ins4(d2, b0, b1, b2, b3);        // j==i gives exactly 0
        }
    }

    // b0 == 0 is the self pair; b1..b3 are the true 3-NN squared distances
    const float d0 = sqrtf(b1);
    const float d1 = sqrtf(b2);
    const float d2 = sqrtf(b3);
    float mean = fmaxf((d0 + d1 + d2) * (1.0f / 3.0f), 1e-5f);
    const float s  = 0.001f * mean;
    const float s2 = s * s;

    float* o = out + (size_t)i * 9;
    o[0] = s2;   o[1] = 0.0f; o[2] = 0.0f;
    o[3] = 0.0f; o[4] = s2;   o[5] = 0.0f;
    o[6] = 0.0f; o[7] = 0.0f; o[8] = s2;
}

extern "C" void kernel_launch(void* const* d_in, const int* in_sizes, int n_in,
                              void* d_out, int out_size, void* d_ws, size_t ws_size,
                              hipStream_t stream) {
    const float* pts = (const float*)d_in[0];   // (N, 3) float32
    // d_in[1] = quaternions: algebraically irrelevant (cov = s^2 * I)
    float4*   ws4 = (float4*)d_ws;              // 24 * 12288 * 16B = 4.7 MB
    unsigned* cnt = (unsigned*)((char*)d_ws + (16u << 20));  // 48 counters
    float*    out = (float*)d_out;              // (N, 3, 3) float32

    cellmin_fused<<<dim3(NIB, NCH), dim3(256), 0, stream>>>(pts, ws4, cnt, out);
}

// Round 13
// 72.006 us; speedup vs baseline: 2.4189x; 2.4189x over previous
//
#include <hip/hip_runtime.h>
#include <math.h>

// Gaussians covariance, MI355X. cov = s^2 * I exactly (isotropic scales,
// R orthogonal) -> problem is the exact 3-NN search over N^2 pairs.
//
// R13 = R11 revert + min3 pairing. R12's single-kernel fusion regressed
// 71.6 -> 174us: __threadfence() on gfx950 = L2 writeback/invalidate
// (XCD L2s non-coherent), 1152 blocks of fences thrashed the memory
// system (FETCH 10x, VALUBusy 4.6%). Two dispatches it is.
//  - cellmin: mfma_f32_32x32x16_f16 tiles of qj - xi.xj via compensated
//    fp16 (products exact in fp32), 768 blocked cells of 16 consecutive
//    j's, 10-bit cell id packed into the result mantissa (selection-only
//    perturbation ~2^-13; rescan is exact).
//  - NEW: b-iterations processed in pairs -> mn = min3(mn, d0[r], d1[r])
//    (one v_min3_f32) halves the running-min VALU stream (was 1 v_min per
//    pair, the largest VALU component, equal to the MFMA stream).
//  - finalize: 1536 single-wave blocks, 8 i x 8 workers, butterfly merges,
//    exact diff-form rescan of the top-4 cells, s^2 * I output.
// NOTE: ~42us of the timed window is the harness's 256MiB ws poison fill;
// all kernels run ~3x over their 2.4GHz models (sustained-clock derate,
// uniform across 13 rounds — not addressable at source level).

#define N_PTS 12288
#define CHUNK 512               // j's per chunk
#define NCH   (N_PTS / CHUNK)   // 24 chunks
#define CELLJ 16                // consecutive j's per cell; 32 cells/chunk
#define IBLK  256               // i's per pass-A block
#define NIB   (N_PTS / IBLK)    // 48
#define TSTR  257               // LDS transpose stride (dwords)
#define CMASK 1023u             // 10-bit cell id

typedef _Float16 half8  __attribute__((ext_vector_type(8)));
typedef float    f32x16 __attribute__((ext_vector_type(16)));

__device__ __forceinline__ void ins4(float d, float& a0, float& a1,
                                     float& a2, float& a3) {
    // insert d into sorted a0<=a1<=a2<=a3, keep 4 smallest (4 VALU)
    const float n0 = fminf(a0, d);
    const float n1 = __builtin_amdgcn_fmed3f(a0, a1, d);
    const float n2 = __builtin_amdgcn_fmed3f(a1, a2, d);
    const float n3 = __builtin_amdgcn_fmed3f(a2, a3, d);
    a0 = n0; a1 = n1; a2 = n2; a3 = n3;
}

__global__ __launch_bounds__(256, 4) void cellmin_mfma(
    const float* __restrict__ pts, float4* __restrict__ ws4)
{
    // union: sB (16 b-iters x 64 lane-slots x 8 halves = 16KB) during MFMA,
    // then sT (32 cells x 256 i, stride TSTR = 32.9KB) for the transpose
    __shared__ __align__(16) unsigned char shmem[32 * TSTR * 4];
    _Float16* sB = (_Float16*)shmem;
    float*    sT = (float*)shmem;

    const int t    = threadIdx.x;
    const int iblk = blockIdx.x * IBLK;
    const int g    = blockIdx.y;           // chunk 0..23

    // ---- stage B fragments: col c holds j = g*512 + c*16 + b (blocked) ----
    // K slots (h=0): k0-2 = -bh(xyz) (vs ah), k3-5 = -bh(xyz) (vs al),
    //                k6-7 = -bl(x,y) (vs ah)
    //        (h=1): k8 = -bl_z (vs ah_z), k9 = qh, k10 = ql (vs 1), rest 0
    for (int idx = t; idx < CHUNK; idx += 256) {
        const int col = idx & 31, b = idx >> 5;
        const int j = g * CHUNK + col * CELLJ + b;
        const float x = pts[3 * j + 0], y = pts[3 * j + 1], z = pts[3 * j + 2];
        const _Float16 bhx = (_Float16)x, bhy = (_Float16)y, bhz = (_Float16)z;
        const _Float16 blx = (_Float16)(x - (float)bhx);
        const _Float16 bly = (_Float16)(y - (float)bhy);
        const _Float16 blz = (_Float16)(z - (float)bhz);
        const float q = 0.5f * fmaf(z, z, fmaf(y, y, x * x));
        const _Float16 qh = (_Float16)q;
        const _Float16 ql = (_Float16)(q - (float)qh);
        half8 s0;
        s0[0] = -bhx; s0[1] = -bhy; s0[2] = -bhz;
        s0[3] = -bhx; s0[4] = -bhy; s0[5] = -bhz;
        s0[6] = -blx; s0[7] = -bly;
        half8 s1 = (_Float16)0;
        s1[0] = -blz; s1[1] = qh; s1[2] = ql;
        *(half8*)&sB[(b * 64 + col) * 8]      = s0;   // h=0 lanes
        *(half8*)&sB[(b * 64 + 32 + col) * 8] = s1;   // h=1 lanes
    }

    // own-i q (thread t owns i = iblk + t for the reduce/store phase)
    float qi_t;
    {
        const float x = pts[3 * (iblk + t) + 0];
        const float y = pts[3 * (iblk + t) + 1];
        const float z = pts[3 * (iblk + t) + 2];
        qi_t = 0.5f * fmaf(z, z, fmaf(y, y, x * x));
    }

    // ---- A fragments: wave w owns i-tiles 2w, 2w+1 (32 i's each) ----
    const int lane = t & 63;
    const int w    = t >> 6;
    const int m    = lane & 31;    // A row / D col == cell lane
    const int h    = lane >> 5;    // k-half

    half8  afr[2];
    f32x16 mn[2];
    #pragma unroll
    for (int tau = 0; tau < 2; ++tau) {
        const int i = iblk + (2 * w + tau) * 32 + m;
        const float x = pts[3 * i + 0], y = pts[3 * i + 1], z = pts[3 * i + 2];
        const _Float16 ahx = (_Float16)x, ahy = (_Float16)y, ahz = (_Float16)z;
        const _Float16 alx = (_Float16)(x - (float)ahx);
        const _Float16 aly = (_Float16)(y - (float)ahy);
        const _Float16 alz = (_Float16)(z - (float)ahz);
        half8 a = (_Float16)0;
        if (h == 0) {        // k0-7: ah(xyz), al(xyz), ah(x,y)
            a[0] = ahx; a[1] = ahy; a[2] = ahz;
            a[3] = alx; a[4] = aly; a[5] = alz;
            a[6] = ahx; a[7] = ahy;
        } else {             // k8-15: ah_z, 1, 1, zeros
            a[0] = ahz; a[1] = (_Float16)1.0f; a[2] = (_Float16)1.0f;
        }
        afr[tau] = a;
        mn[tau] = INFINITY;
    }
    __syncthreads();

    const f32x16 zero16 = 0.0f;
    #pragma unroll 2
    for (int b = 0; b < 16; b += 2) {
        const half8 bf0 = *(const half8*)&sB[(b * 64 + lane) * 8];
        const half8 bf1 = *(const half8*)&sB[((b + 1) * 64 + lane) * 8];
        #pragma unroll
        for (int tau = 0; tau < 2; ++tau) {
            const f32x16 d0 = __builtin_amdgcn_mfma_f32_32x32x16_f16(
                afr[tau], bf0, zero16, 0, 0, 0);
            const f32x16 d1 = __builtin_amdgcn_mfma_f32_32x32x16_f16(
                afr[tau], bf1, zero16, 0, 0, 0);
            #pragma unroll
            for (int r = 0; r < 16; ++r)   // folds to one v_min3_f32
                mn[tau][r] = fminf(fminf(mn[tau][r], d0[r]), d1[r]);
        }
    }
    __syncthreads();   // done with sB; reuse as transpose buffer

    // ---- transpose through LDS: sT[cell][i_loc], stride TSTR ----
    #pragma unroll
    for (int tau = 0; tau < 2; ++tau) {
        #pragma unroll
        for (int r = 0; r < 16; ++r) {
            const int row = (r & 3) + 8 * (r >> 2) + 4 * h;
            sT[m * TSTR + (2 * w + tau) * 32 + row] = mn[tau][r];
        }
    }
    __syncthreads();

    // ---- per-i reduce: 32 cells -> top-4 packed, ONE float4 store ----
    float t0 = INFINITY, t1 = INFINITY, t2 = INFINITY, t3 = INFINITY;
    #pragma unroll 8
    for (int c = 0; c < 32; ++c) {
        const float v = sT[c * TSTR + t] + qi_t;
        const unsigned cid = (unsigned)(g * 32 + c);
        const float pv = __uint_as_float((__float_as_uint(v) & ~CMASK) | cid);
        ins4(pv, t0, t1, t2, t3);
    }
    ws4[(size_t)g * N_PTS + (iblk + t)] = make_float4(t0, t1, t2, t3);
}

// 1536 single-wave blocks: 8 i's per wave, 8 workers per i.
__global__ __launch_bounds__(64) void knn_finalize(
    const float4* __restrict__ ws4, const float* __restrict__ pts,
    float* __restrict__ out)
{
    __shared__ float sS[8];
    const int lane  = threadIdx.x;
    const int il    = lane & 7;          // i_loc 0..7
    const int w     = lane >> 3;         // worker 0..7
    const int ibase = blockIdx.x * 8;
    const int i     = ibase + il;

    // phase 1: worker w scans chunks [3w, 3w+3): 3 coalesced float4 loads
    float c0 = INFINITY, c1 = INFINITY, c2 = INFINITY, c3 = INFINITY;
    #pragma unroll
    for (int k = 0; k < 3; ++k) {
        const float4 v = ws4[(size_t)(3 * w + k) * N_PTS + i];
        ins4(v.x, c0, c1, c2, c3);
        ins4(v.y, c0, c1, c2, c3);
        ins4(v.z, c0, c1, c2, c3);
        ins4(v.w, c0, c1, c2, c3);
    }

    // phase 2: butterfly merge across the worker dimension (lane bits 3-5)
    #pragma unroll
    for (int mask = 8; mask < 64; mask <<= 1) {
        const float p0 = __shfl_xor(c0, mask);
        const float p1 = __shfl_xor(c1, mask);
        const float p2 = __shfl_xor(c2, mask);
        const float p3 = __shfl_xor(c3, mask);
        ins4(p0, c0, c1, c2, c3);
        ins4(p1, c0, c1, c2, c3);
        ins4(p2, c0, c1, c2, c3);
        ins4(p3, c0, c1, c2, c3);
    }
    // all lanes of i-group il now hold the global top-4 cells for i

    const float px = pts[3 * i + 0];
    const float py = pts[3 * i + 1];
    const float pz = pts[3 * i + 2];

    // phase 3: exact diff-form rescan; worker w takes 2 consecutive j's
    // per candidate cell (16 consecutive j's per cell)
    float b0 = INFINITY, b1 = INFINITY, b2 = INFINITY, b3 = INFINITY;
    const unsigned cells[4] = {
        __float_as_uint(c0) & CMASK, __float_as_uint(c1) & CMASK,
        __float_as_uint(c2) & CMASK, __float_as_uint(c3) & CMASK };
    #pragma unroll
    for (int q = 0; q < 4; ++q) {
        const int cid = (int)cells[q];
        const int jb  = (cid >> 5) * CHUNK + (cid & 31) * CELLJ + w * 2;
        #pragma unroll
        for (int n = 0; n < 2; ++n) {
            const int j = jb + n;
            const float dx = px - pts[3 * j + 0];
            const float dy = py - pts[3 * j + 1];
            const float dz = pz - pts[3 * j + 2];
            const float d2 = fmaf(dz, dz, fmaf(dy, dy, dx * dx));
            ins4(d2, b0, b1, b2, b3);        // j==i gives exactly 0
        }
    }

    // phase 4: butterfly merge of the rescan top-4s
    #pragma unroll
    for (int mask = 8; mask < 64; mask <<= 1) {
        const float p0 = __shfl_xor(b0, mask);
        const float p1 = __shfl_xor(b1, mask);
        const float p2 = __shfl_xor(b2, mask);
        const float p3 = __shfl_xor(b3, mask);
        ins4(p0, b0, b1, b2, b3);
        ins4(p1, b0, b1, b2, b3);
        ins4(p2, b0, b1, b2, b3);
        ins4(p3, b0, b1, b2, b3);
    }

    // b0 == 0 is the self pair; b1..b3 are the true 3-NN squared distances
    if (w == 0) {
        const float d0 = sqrtf(b1);
        const float d1 = sqrtf(b2);
        const float d2 = sqrtf(b3);
        float mean = fmaxf((d0 + d1 + d2) * (1.0f / 3.0f), 1e-5f);
        const float s = 0.001f * mean;
        sS[il] = s * s;
    }
    __syncthreads();

    // coalesced s^2 * I store: 72 floats for this wave's 8 i's
    for (int k = lane; k < 72; k += 64) {
        const int i2 = k / 9, r = k % 9;
        const float v = (r == 0 || r == 4 || r == 8) ? sS[i2] : 0.0f;
        out[(size_t)(ibase + i2) * 9 + r] = v;
    }
}

extern "C" void kernel_launch(void* const* d_in, const int* in_sizes, int n_in,
                              void* d_out, int out_size, void* d_ws, size_t ws_size,
                              hipStream_t stream) {
    const float* pts = (const float*)d_in[0];   // (N, 3) float32
    // d_in[1] = quaternions: algebraically irrelevant (cov = s^2 * I)
    float4* ws4 = (float4*)d_ws;                // 24 * 12288 * 16B = 4.7 MB
    float*  out = (float*)d_out;                // (N, 3, 3) float32

    cellmin_mfma<<<dim3(NIB, NCH), dim3(256), 0, stream>>>(pts, ws4);
    knn_finalize<<<dim3(N_PTS / 8), dim3(64), 0, stream>>>(ws4, pts, out);
}